// Round 5
// baseline (659.876 us; speedup 1.0000x reference)
//
#include <hip/hip_runtime.h>
#include <hip/hip_bf16.h>

#define N_NODES  100000
#define N_EDGES  1600000
#define IN_CH    128
#define HID      32
#define N_GRAPHS 64

// workspace layout (float element offsets) — total ~26.41 MB
#define OFF_H     0            // float[100000*32]  h1 -> relu(h1) -> h2 (in-place)
#define OFF_AGG   3200000      // float[100000*32]  scatter accumulator
#define OFF_DINV  6400000      // float[100000]
#define OFF_DEG   6500000      // int[100000]
#define OFF_GSUM  6600000      // float[64*32]
#define OFF_CNT   6602048      // float[64]
#define OFF_FLAG  6602112      // int[1]: 1 = float inputs are bf16, 0 = fp32
// end: 6602113 floats = 26,408,452 bytes

#define POOL_NODES 1024

// dtype-adaptive float load (flag resolved at runtime; evidence says fp32)
__device__ __forceinline__ float ldf(const void* p, long i, int bf) {
    if (bf) return __bfloat162float(((const __hip_bfloat16*)p)[i]);
    return ((const float*)p)[i];
}

// Detect input float dtype by reading x as bf16: genuine bf16 N(0,1) stays
// |v|<6; fp32 low mantissa halves decode as |v|>=1e4 or NaN w.p. ~0.45/elem.
__global__ void flag_kernel(const void* __restrict__ x, int* __restrict__ flag) {
    if (threadIdx.x == 0 && blockIdx.x == 0) {
        const __hip_bfloat16* xb = (const __hip_bfloat16*)x;
        int bf = 1;
        for (int i = 0; i < 256; ++i) {
            float v = fabsf(__bfloat162float(xb[i]));
            if (!(v < 1e4f)) bf = 0;   // catches NaN too
        }
        *flag = bf;
    }
}

__global__ void deg_kernel(const int* __restrict__ dst, int* __restrict__ deg) {
    int e = blockIdx.x * blockDim.x + threadIdx.x;
    if (e < N_EDGES) {
        int d = dst[e];
        if ((unsigned)d < N_NODES) atomicAdd(&deg[d], 1);
    }
}

__global__ void dinv_kernel(const int* __restrict__ deg, float* __restrict__ dinv) {
    int i = blockIdx.x * blockDim.x + threadIdx.x;
    if (i < N_NODES) dinv[i] = rsqrtf((float)(deg[i] + 1));  // +1 self-loop
}

// h = x @ W1   (x: [N,128], W1: [128,32] -> h fp32)
__global__ __launch_bounds__(256) void gemm1_kernel(const void* __restrict__ x,
                                                    const void* __restrict__ W1,
                                                    float* __restrict__ h,
                                                    const int* __restrict__ flag) {
    __shared__ float Wl[IN_CH * HID];   // 16 KB
    __shared__ float xs[8 * IN_CH];     // 4 KB
    const int bf = *flag;
    int tid = threadIdx.x;
    for (int j = tid; j < IN_CH * HID; j += 256) Wl[j] = ldf(W1, j, bf);
    int row0 = blockIdx.x * 8;          // N_NODES % 8 == 0
    for (int j = tid; j < 8 * IN_CH; j += 256) {
        int r = j >> 7, k = j & 127;
        xs[j] = ldf(x, (long)(row0 + r) * IN_CH + k, bf);
    }
    __syncthreads();
    int r = tid >> 5, c = tid & 31;
    const float* xr = &xs[r * IN_CH];
    float acc = 0.f;
    #pragma unroll 8
    for (int k = 0; k < IN_CH; ++k) acc += xr[k] * Wl[k * HID + c];
    h[(row0 + r) * HID + c] = acc;
}

// h = h @ W2 IN PLACE (blocks stage then overwrite disjoint rows)
__global__ __launch_bounds__(256) void gemm2_kernel(float* __restrict__ h,
                                                    const void* __restrict__ W2,
                                                    const int* __restrict__ flag) {
    __shared__ float Wl[HID * HID];
    __shared__ float xs[8 * HID];
    const int bf = *flag;
    int tid = threadIdx.x;
    for (int j = tid; j < HID * HID; j += 256) Wl[j] = ldf(W2, j, bf);
    int row0 = blockIdx.x * 8;
    xs[tid] = h[(long)row0 * HID + tid];
    __syncthreads();
    int r = tid >> 5, c = tid & 31;
    float acc = 0.f;
    #pragma unroll
    for (int k = 0; k < HID; ++k) acc += xs[r * HID + k] * Wl[k * HID + c];
    h[(long)(row0 + r) * HID + c] = acc;
}

// scatter-add: agg[dst] += h[src] * dinv[src]*dinv[dst], one (edge,channel)/thread
__global__ __launch_bounds__(256) void agg_kernel(const int* __restrict__ src,
                                                  const int* __restrict__ dst,
                                                  const float* __restrict__ dinv,
                                                  const float* __restrict__ h,
                                                  float* __restrict__ agg) {
    int gid = blockIdx.x * 256 + threadIdx.x;
    int e = gid >> 5, c = gid & 31;
    if (e < N_EDGES) {
        int s = src[e], d = dst[e];
        float w = dinv[s] * dinv[d];
        atomicAdd(&agg[(long)d * HID + c], h[(long)s * HID + c] * w);
    }
}

// h = relu(agg + h*dinv^2 + b1), in place
__global__ void combine1_kernel(const float* __restrict__ agg, float* __restrict__ h,
                                const float* __restrict__ dinv,
                                const void* __restrict__ b1,
                                const int* __restrict__ flag) {
    const int bf = *flag;
    int gid = blockIdx.x * blockDim.x + threadIdx.x;
    if (gid < N_NODES * HID) {
        int i = gid >> 5, c = gid & 31;
        float di = dinv[i];
        float v = agg[gid] + h[gid] * di * di + ldf(b1, c, bf);
        h[gid] = fmaxf(v, 0.f);
    }
}

// out_h = agg + h*dinv^2 + b2 (FP32 out), plus per-graph pooled sums via LDS.
__global__ __launch_bounds__(256) void combine2_pool_kernel(const float* __restrict__ agg,
                                                            const float* __restrict__ h,
                                                            const float* __restrict__ dinv,
                                                            const void* __restrict__ b2,
                                                            const int* __restrict__ batch,
                                                            float* __restrict__ out_h,
                                                            float* __restrict__ gsum,
                                                            float* __restrict__ cnt,
                                                            const int* __restrict__ flag) {
    __shared__ float pool[N_GRAPHS * HID];  // 8 KB
    __shared__ float cntl[N_GRAPHS];
    const int bf = *flag;
    int tid = threadIdx.x;
    for (int j = tid; j < N_GRAPHS * HID; j += 256) pool[j] = 0.f;
    if (tid < N_GRAPHS) cntl[tid] = 0.f;
    __syncthreads();
    int start = blockIdx.x * POOL_NODES;
    int end = min(start + POOL_NODES, N_NODES);
    int c = tid & 31;
    for (int nb = start + (tid >> 5); nb < end; nb += 8) {
        float di = dinv[nb];
        float v = agg[(long)nb * HID + c] + h[(long)nb * HID + c] * di * di
                  + ldf(b2, c, bf);
        out_h[(long)nb * HID + c] = v;
        int g = batch[nb];
        if ((unsigned)g < N_GRAPHS) {   // segment_sum drops OOB ids
            atomicAdd(&pool[g * HID + c], v);
            if (c == 0) atomicAdd(&cntl[g], 1.f);
        }
    }
    __syncthreads();
    for (int j = tid; j < N_GRAPHS * HID; j += 256)
        atomicAdd(&gsum[j], pool[j]);
    if (tid < N_GRAPHS)
        atomicAdd(&cnt[tid], cntl[tid]);
}

// summary = (gsum/cnt) @ Ws + bs  (FP32 out)
__global__ void summary_kernel(const float* __restrict__ gsum, const float* __restrict__ cnt,
                               const void* __restrict__ Ws,
                               const void* __restrict__ bs,
                               float* __restrict__ out,
                               const int* __restrict__ flag) {
    const int bf = *flag;
    int g = blockIdx.x, c = threadIdx.x;
    float inv = 1.f / fmaxf(cnt[g], 1.f);
    float acc = ldf(bs, c, bf);
    #pragma unroll
    for (int k = 0; k < HID; ++k)
        acc += gsum[g * HID + k] * inv * ldf(Ws, k * HID + c, bf);
    out[g * HID + c] = acc;
}

extern "C" void kernel_launch(void* const* d_in, const int* in_sizes, int n_in,
                              void* d_out, int out_size, void* d_ws, size_t ws_size,
                              hipStream_t stream) {
    const void* x    = d_in[0];
    const int* edge  = (const int*)d_in[1];
    const int* src   = edge;
    const int* dst   = edge + N_EDGES;
    const int* batch = (const int*)d_in[2];
    const void* W1   = d_in[3];
    const void* b1   = d_in[4];
    const void* W2   = d_in[5];
    const void* b2   = d_in[6];
    const void* Ws   = d_in[7];
    const void* bs   = d_in[8];

    float* ws   = (float*)d_ws;
    float* h    = ws + OFF_H;
    float* agg  = ws + OFF_AGG;
    float* dinv = ws + OFF_DINV;
    int*   deg  = (int*)(ws + OFF_DEG);
    float* gsum = ws + OFF_GSUM;
    float* cnt  = ws + OFF_CNT;
    int*   flag = (int*)(ws + OFF_FLAG);

    float* out     = (float*)d_out;
    float* out_sum = out;                    // [64,32] fp32
    float* out_h   = out + N_GRAPHS * HID;   // [100000,32] fp32

    flag_kernel<<<1, 64, 0, stream>>>(x, flag);

    hipMemsetAsync(deg, 0, N_NODES * sizeof(int), stream);
    deg_kernel<<<(N_EDGES + 255) / 256, 256, 0, stream>>>(dst, deg);
    dinv_kernel<<<(N_NODES + 255) / 256, 256, 0, stream>>>(deg, dinv);

    gemm1_kernel<<<N_NODES / 8, 256, 0, stream>>>(x, W1, h, flag);

    hipMemsetAsync(agg, 0, (size_t)N_NODES * HID * sizeof(float), stream);
    agg_kernel<<<(N_EDGES * 32) / 256, 256, 0, stream>>>(src, dst, dinv, h, agg);
    combine1_kernel<<<(N_NODES * HID) / 256, 256, 0, stream>>>(agg, h, dinv, b1, flag);

    gemm2_kernel<<<N_NODES / 8, 256, 0, stream>>>(h, W2, flag);

    hipMemsetAsync(agg, 0, (size_t)N_NODES * HID * sizeof(float), stream);
    agg_kernel<<<(N_EDGES * 32) / 256, 256, 0, stream>>>(src, dst, dinv, h, agg);

    hipMemsetAsync(gsum, 0, (N_GRAPHS * HID + N_GRAPHS) * sizeof(float), stream);
    combine2_pool_kernel<<<(N_NODES + POOL_NODES - 1) / POOL_NODES, 256, 0, stream>>>(
        agg, h, dinv, b2, batch, out_h, gsum, cnt, flag);
    summary_kernel<<<N_GRAPHS, HID, 0, stream>>>(gsum, cnt, Ws, bs, out_sum, flag);
}

// Round 6
// 583.088 us; speedup vs baseline: 1.1317x; 1.1317x over previous
//
#include <hip/hip_runtime.h>
#include <hip/hip_bf16.h>

#define N_NODES  100000
#define N_EDGES  1600000
#define IN_CH    128
#define HID      32
#define N_GRAPHS 64
#define NB       391          // ceil(100000/256) scan blocks

// workspace layout (float/int element offsets) — total ~20.8 MB
#define OFF_A      0          // float[100000*32]  h1, then h3 (=relu(h1+..)@W2)
#define OFF_CSR    3200000    // int[1600000]      incoming-edge src ids, CSR order
#define OFF_ROWPTR 4800000    // int[100001]
#define OFF_CURSOR 4900032    // int[100000]
#define OFF_DEG    5000064    // int[100000]
#define OFF_DINV   5100096    // float[100000]
#define OFF_INCL   5200128    // int[512]  inclusive block sums
#define OFF_GSUM   5200640    // float[64*32]
#define OFF_CNT    5202688    // float[64]
// end: 5202752 floats = 20,811,008 bytes

#define POOL_NODES 1024

__global__ void deg_kernel(const int* __restrict__ dst, int* __restrict__ deg) {
    int e = blockIdx.x * blockDim.x + threadIdx.x;
    if (e < N_EDGES) {
        int d = dst[e];
        if ((unsigned)d < N_NODES) atomicAdd(&deg[d], 1);
    }
}

__global__ void dinv_kernel(const int* __restrict__ deg, float* __restrict__ dinv) {
    int i = blockIdx.x * blockDim.x + threadIdx.x;
    if (i < N_NODES) dinv[i] = rsqrtf((float)(deg[i] + 1));  // +1 self-loop
}

// ---- 3-stage exclusive prefix scan of deg -> row_ptr (+cursor copy) ----
__global__ void scan1_kernel(const int* __restrict__ deg, int* __restrict__ bsum) {
    __shared__ int s[256];
    int t = threadIdx.x, i = blockIdx.x * 256 + t;
    s[t] = (i < N_NODES) ? deg[i] : 0;
    __syncthreads();
    for (int off = 128; off > 0; off >>= 1) {
        if (t < off) s[t] += s[t + off];
        __syncthreads();
    }
    if (t == 0) bsum[blockIdx.x] = s[0];
}

__global__ void scan2_kernel(int* __restrict__ bsum) {   // in-place inclusive scan, 512 wide
    __shared__ int s[512];
    int t = threadIdx.x;
    s[t] = (t < NB) ? bsum[t] : 0;
    __syncthreads();
    for (int off = 1; off < 512; off <<= 1) {
        int v = (t >= off) ? s[t - off] : 0;
        __syncthreads();
        s[t] += v;
        __syncthreads();
    }
    if (t < NB) bsum[t] = s[t];
}

__global__ void scan3_kernel(const int* __restrict__ deg, const int* __restrict__ incl,
                             int* __restrict__ row_ptr, int* __restrict__ cursor) {
    __shared__ int s[256];
    int t = threadIdx.x, b = blockIdx.x, i = b * 256 + t;
    int v = (i < N_NODES) ? deg[i] : 0;
    s[t] = v;
    __syncthreads();
    for (int off = 1; off < 256; off <<= 1) {
        int x = (t >= off) ? s[t - off] : 0;
        __syncthreads();
        s[t] += x;
        __syncthreads();
    }
    int base = (b > 0) ? incl[b - 1] : 0;
    if (i < N_NODES) {
        int row = base + s[t] - v;          // exclusive
        row_ptr[i] = row;
        cursor[i]  = row;
        if (i == N_NODES - 1) row_ptr[N_NODES] = base + s[t];
    }
}

__global__ void scatter_kernel(const int* __restrict__ src, const int* __restrict__ dst,
                               int* __restrict__ cursor, int* __restrict__ csr) {
    int e = blockIdx.x * blockDim.x + threadIdx.x;
    if (e < N_EDGES) {
        int d = dst[e];
        if ((unsigned)d < N_NODES) {
            int pos = atomicAdd(&cursor[d], 1);
            csr[pos] = src[e];
        }
    }
}

// A = x @ W1   (fp32, float4-staged)
__global__ __launch_bounds__(256) void gemm1_kernel(const float* __restrict__ x,
                                                    const float* __restrict__ W1,
                                                    float* __restrict__ A) {
    __shared__ float Wl[IN_CH * HID];   // 16 KB
    __shared__ float xs[8 * IN_CH];     // 4 KB
    int tid = threadIdx.x;
    const float4* W4 = (const float4*)W1;
    for (int j = tid; j < IN_CH * HID / 4; j += 256) ((float4*)Wl)[j] = W4[j];
    ((float4*)xs)[tid] = ((const float4*)x)[blockIdx.x * 256 + tid];  // 8 rows
    __syncthreads();
    int r = tid >> 5, c = tid & 31;
    const float* xr = &xs[r * IN_CH];
    float acc = 0.f;
    #pragma unroll 8
    for (int k = 0; k < IN_CH; ++k) acc += xr[k] * Wl[k * HID + c];
    A[(blockIdx.x * 8 + r) * HID + c] = acc;
}

// out = relu( sum_in-edges A[s]*dinv[s]*dinv[d] + A[d]*dinv[d]^2 + b1 )
__global__ __launch_bounds__(256) void layer1_kernel(const float* __restrict__ A,
                                                     const int* __restrict__ csr,
                                                     const int* __restrict__ row_ptr,
                                                     const float* __restrict__ dinv,
                                                     const float* __restrict__ b1,
                                                     float* __restrict__ out) {
    int tid = threadIdx.x;
    int node = blockIdx.x * 8 + (tid >> 5);
    int c = tid & 31;
    if (node >= N_NODES) return;
    float dd = dinv[node];
    float acc = A[(size_t)node * HID + c] * dd * dd + b1[c];
    int j = row_ptr[node], re = row_ptr[node + 1];
    for (; j < re; ++j) {
        int s = csr[j];
        acc += A[(size_t)s * HID + c] * (dinv[s] * dd);
    }
    out[(size_t)node * HID + c] = fmaxf(acc, 0.f);
}

// A = in @ W2  (in = d_out h-region, out = ws A; disjoint buffers)
__global__ __launch_bounds__(256) void gemm2_kernel(const float* __restrict__ in,
                                                    const float* __restrict__ W2,
                                                    float* __restrict__ A) {
    __shared__ float Wl[HID * HID];     // 4 KB
    __shared__ float xs[8 * HID];       // 1 KB
    int tid = threadIdx.x;
    ((float4*)Wl)[tid] = ((const float4*)W2)[tid];        // 1024 floats
    xs[tid] = in[(size_t)blockIdx.x * 256 + tid];         // 8 rows
    __syncthreads();
    int r = tid >> 5, c = tid & 31;
    float acc = 0.f;
    #pragma unroll
    for (int k = 0; k < HID; ++k) acc += xs[r * HID + k] * Wl[k * HID + c];
    A[(size_t)(blockIdx.x * 8 + r) * HID + c] = acc;
}

// out = sum_in-edges A[s]*dinv[s]*dinv[d] + A[d]*dinv[d]^2 + b2   (no relu)
__global__ __launch_bounds__(256) void layer2_kernel(const float* __restrict__ A,
                                                     const int* __restrict__ csr,
                                                     const int* __restrict__ row_ptr,
                                                     const float* __restrict__ dinv,
                                                     const float* __restrict__ b2,
                                                     float* __restrict__ out) {
    int tid = threadIdx.x;
    int node = blockIdx.x * 8 + (tid >> 5);
    int c = tid & 31;
    if (node >= N_NODES) return;
    float dd = dinv[node];
    float acc = A[(size_t)node * HID + c] * dd * dd + b2[c];
    int j = row_ptr[node], re = row_ptr[node + 1];
    for (; j < re; ++j) {
        int s = csr[j];
        acc += A[(size_t)s * HID + c] * (dinv[s] * dd);
    }
    out[(size_t)node * HID + c] = acc;
}

// per-graph mean-pool inputs: gsum += h, cnt += 1 (LDS-staged; no sortedness assumption)
__global__ __launch_bounds__(256) void pool_kernel(const float* __restrict__ h,
                                                   const int* __restrict__ batch,
                                                   float* __restrict__ gsum,
                                                   float* __restrict__ cnt) {
    __shared__ float pool[N_GRAPHS * HID];  // 8 KB
    __shared__ float cntl[N_GRAPHS];
    int tid = threadIdx.x;
    for (int j = tid; j < N_GRAPHS * HID; j += 256) pool[j] = 0.f;
    if (tid < N_GRAPHS) cntl[tid] = 0.f;
    __syncthreads();
    int start = blockIdx.x * POOL_NODES;
    int end = min(start + POOL_NODES, N_NODES);
    int c = tid & 31;
    for (int nb = start + (tid >> 5); nb < end; nb += 8) {
        float v = h[(size_t)nb * HID + c];
        int g = batch[nb];
        if ((unsigned)g < N_GRAPHS) {
            atomicAdd(&pool[g * HID + c], v);
            if (c == 0) atomicAdd(&cntl[g], 1.f);
        }
    }
    __syncthreads();
    for (int j = tid; j < N_GRAPHS * HID; j += 256) atomicAdd(&gsum[j], pool[j]);
    if (tid < N_GRAPHS) atomicAdd(&cnt[tid], cntl[tid]);
}

// summary = (gsum/cnt) @ Ws + bs
__global__ void summary_kernel(const float* __restrict__ gsum, const float* __restrict__ cnt,
                               const float* __restrict__ Ws, const float* __restrict__ bs,
                               float* __restrict__ out) {
    int g = blockIdx.x, c = threadIdx.x;
    float inv = 1.f / fmaxf(cnt[g], 1.f);
    float acc = bs[c];
    #pragma unroll
    for (int k = 0; k < HID; ++k)
        acc += gsum[g * HID + k] * inv * Ws[k * HID + c];
    out[g * HID + c] = acc;
}

extern "C" void kernel_launch(void* const* d_in, const int* in_sizes, int n_in,
                              void* d_out, int out_size, void* d_ws, size_t ws_size,
                              hipStream_t stream) {
    const float* x    = (const float*)d_in[0];
    const int* edge   = (const int*)d_in[1];
    const int* src    = edge;
    const int* dst    = edge + N_EDGES;
    const int* batch  = (const int*)d_in[2];
    const float* W1   = (const float*)d_in[3];
    const float* b1   = (const float*)d_in[4];
    const float* W2   = (const float*)d_in[5];
    const float* b2   = (const float*)d_in[6];
    const float* Ws   = (const float*)d_in[7];
    const float* bs   = (const float*)d_in[8];

    float* ws      = (float*)d_ws;
    float* A       = ws + OFF_A;
    int*   csr     = (int*)(ws + OFF_CSR);
    int*   row_ptr = (int*)(ws + OFF_ROWPTR);
    int*   cursor  = (int*)(ws + OFF_CURSOR);
    int*   deg     = (int*)(ws + OFF_DEG);
    float* dinv    = ws + OFF_DINV;
    int*   incl    = (int*)(ws + OFF_INCL);
    float* gsum    = ws + OFF_GSUM;
    float* cnt     = ws + OFF_CNT;

    float* out     = (float*)d_out;
    float* out_sum = out;                    // [64,32]
    float* out_h   = out + N_GRAPHS * HID;   // [100000,32] — also used as h2 scratch

    // degree + norm
    hipMemsetAsync(deg, 0, N_NODES * sizeof(int), stream);
    deg_kernel<<<(N_EDGES + 255) / 256, 256, 0, stream>>>(dst, deg);
    dinv_kernel<<<NB, 256, 0, stream>>>(deg, dinv);

    // CSR build: scan + scatter (int atomics only)
    scan1_kernel<<<NB, 256, 0, stream>>>(deg, incl);
    scan2_kernel<<<1, 512, 0, stream>>>(incl);
    scan3_kernel<<<NB, 256, 0, stream>>>(deg, incl, row_ptr, cursor);
    scatter_kernel<<<(N_EDGES + 255) / 256, 256, 0, stream>>>(src, dst, cursor, csr);

    // layer 1: A = x@W1 ; out_h = relu(gather(A) + self + b1)
    gemm1_kernel<<<N_NODES / 8, 256, 0, stream>>>(x, W1, A);
    layer1_kernel<<<N_NODES / 8, 256, 0, stream>>>(A, csr, row_ptr, dinv, b1, out_h);

    // layer 2: A = out_h@W2 ; out_h = gather(A) + self + b2
    gemm2_kernel<<<N_NODES / 8, 256, 0, stream>>>(out_h, W2, A);
    layer2_kernel<<<N_NODES / 8, 256, 0, stream>>>(A, csr, row_ptr, dinv, b2, out_h);

    // pooling + summary
    hipMemsetAsync(gsum, 0, (N_GRAPHS * HID + N_GRAPHS) * sizeof(float), stream);
    pool_kernel<<<(N_NODES + POOL_NODES - 1) / POOL_NODES, 256, 0, stream>>>(out_h, batch, gsum, cnt);
    summary_kernel<<<N_GRAPHS, HID, 0, stream>>>(gsum, cnt, Ws, bs, out_sum);
}

// Round 7
// 417.902 us; speedup vs baseline: 1.5790x; 1.3953x over previous
//
#include <hip/hip_runtime.h>

#define N_NODES  100000
#define N_EDGES  1600000
#define IN_CH    128
#define HID      32
#define N_GRAPHS 64

#define NBIN   391            // bins of 256 dst nodes: bin = dst >> 8
#define CHUNK  4096           // edges per multisplit block; grid = 391
#define MGRID  391            // ceil(1.6M / 4096)
#define STG    5120           // csr2 per-bin staging capacity (mean 4096, 16 sigma margin)

// workspace layout (4-byte element offsets) — total 26,403,140 B
#define OFF_B      0          // float[3,200,000]  scaled features; H[391*391] aliases head until msplit done
#define OFF_EDGEPK 3200000    // int[1,600,000]    bin-grouped packed edges; gsum/cnt alias head after csr2
#define OFF_CSR    4800000    // int[1,600,000]    per-node CSR src ids
#define OFF_COLT   6400000    // int[391]
#define OFF_BINB   6400391    // int[392]
#define OFF_ROWPTR 6400784    // int[100,001]
#define OFF_DINV   6500785    // float[100,000]
// end: 6,600,785 elems

#define POOL_NODES 1024

// ---------- phase 1: per-(bin, wg) histogram (no global atomics) ----------
__global__ __launch_bounds__(512) void hist_kernel(const int* __restrict__ dst,
                                                   int* __restrict__ H) {
    __shared__ int s[512];
    int t = threadIdx.x, wg = blockIdx.x;
    s[t] = 0;
    __syncthreads();
    int e0 = wg * CHUNK, e1 = min(e0 + CHUNK, N_EDGES);
    for (int e = e0 + t; e < e1; e += 512) {
        int d = dst[e];
        if ((unsigned)d < N_NODES) atomicAdd(&s[d >> 8], 1);
    }
    __syncthreads();
    if (t < NBIN) H[t * MGRID + wg] = s[t];   // H[bin][wg]
}

// ---------- phase 2a: exclusive scan each bin-row across wgs (in place) ----------
__global__ __launch_bounds__(512) void scanrow_kernel(int* __restrict__ H,
                                                      int* __restrict__ colT) {
    __shared__ int s[512];
    int t = threadIdx.x, bin = blockIdx.x;
    s[t] = (t < MGRID) ? H[bin * MGRID + t] : 0;
    __syncthreads();
    for (int off = 1; off < 512; off <<= 1) {
        int v = (t >= off) ? s[t - off] : 0;
        __syncthreads();
        if (t >= off) s[t] += v;
        __syncthreads();
    }
    if (t < MGRID) H[bin * MGRID + t] = t ? s[t - 1] : 0;   // exclusive
    if (t == 0) colT[bin] = s[MGRID - 1];
}

// ---------- phase 2b: scan bin totals -> bin bases ----------
__global__ __launch_bounds__(512) void scanbase_kernel(const int* __restrict__ colT,
                                                       int* __restrict__ binB,
                                                       int* __restrict__ row_ptr) {
    __shared__ int s[512];
    int t = threadIdx.x;
    s[t] = (t < NBIN) ? colT[t] : 0;
    __syncthreads();
    for (int off = 1; off < 512; off <<= 1) {
        int v = (t >= off) ? s[t - off] : 0;
        __syncthreads();
        if (t >= off) s[t] += v;
        __syncthreads();
    }
    if (t < NBIN) binB[t] = t ? s[t - 1] : 0;
    if (t == 0) { binB[NBIN] = s[NBIN - 1]; row_ptr[N_NODES] = s[NBIN - 1]; }
}

// ---------- phase 3: bin-grouped scatter with LDS staging (coalesced flush) ----------
__global__ __launch_bounds__(512) void msplit_kernel(const int* __restrict__ src,
                                                     const int* __restrict__ dst,
                                                     const int* __restrict__ H,
                                                     const int* __restrict__ binB,
                                                     int* __restrict__ edgepk) {
    __shared__ int s[512];          // hist -> inclusive scan
    __shared__ int cur[NBIN];
    __shared__ int gb[NBIN];
    __shared__ int stage[CHUNK];
    __shared__ int gof[CHUNK];
    int t = threadIdx.x, wg = blockIdx.x;
    s[t] = 0;
    __syncthreads();
    int e0 = wg * CHUNK, e1 = min(e0 + CHUNK, N_EDGES);
    for (int e = e0 + t; e < e1; e += 512) {
        int d = dst[e];
        if ((unsigned)d < N_NODES) atomicAdd(&s[d >> 8], 1);
    }
    __syncthreads();
    for (int off = 1; off < 512; off <<= 1) {
        int v = (t >= off) ? s[t - off] : 0;
        __syncthreads();
        if (t >= off) s[t] += v;
        __syncthreads();
    }
    if (t < NBIN) {
        int lo = t ? s[t - 1] : 0;
        cur[t] = lo;
        gb[t] = binB[t] + H[t * MGRID + wg] - lo;   // global base minus local base
    }
    __syncthreads();
    for (int e = e0 + t; e < e1; e += 512) {
        int d = dst[e];
        if ((unsigned)d < N_NODES) {
            int b = d >> 8;
            int p = atomicAdd(&cur[b], 1);
            stage[p] = (src[e] << 8) | (d & 255);
            gof[p] = gb[b];
        }
    }
    __syncthreads();
    int total = s[511];
    for (int p = t; p < total; p += 512)
        edgepk[gof[p] + p] = stage[p];
}

// ---------- phase 4: within-bin reorder -> exact CSR + deg/dinv/row_ptr ----------
__global__ __launch_bounds__(256) void csr2_kernel(const int* __restrict__ edgepk,
                                                   const int* __restrict__ binB,
                                                   int* __restrict__ row_ptr,
                                                   float* __restrict__ dinv,
                                                   int* __restrict__ csr) {
    __shared__ int cnt[256], s[256], cur[256];
    __shared__ int stage[STG];
    int t = threadIdx.x, bin = blockIdx.x;
    int ebase = binB[bin], eend = binB[bin + 1];
    int n = eend - ebase;
    cnt[t] = 0;
    __syncthreads();
    for (int p = ebase + t; p < eend; p += 256)
        atomicAdd(&cnt[edgepk[p] & 255], 1);
    __syncthreads();
    s[t] = cnt[t];
    __syncthreads();
    for (int off = 1; off < 256; off <<= 1) {
        int v = (t >= off) ? s[t - off] : 0;
        __syncthreads();
        if (t >= off) s[t] += v;
        __syncthreads();
    }
    int excl = t ? s[t - 1] : 0;
    int node = (bin << 8) + t;
    if (node < N_NODES) {
        dinv[node] = rsqrtf((float)(cnt[t] + 1));   // +1 self-loop
        row_ptr[node] = ebase + excl;
    }
    cur[t] = excl;
    __syncthreads();
    for (int p = ebase + t; p < eend; p += 256) {
        int w = edgepk[p];
        int l = atomicAdd(&cur[w & 255], 1);
        int sv = w >> 8;
        if (l < STG) stage[l] = sv;
        else csr[ebase + l] = sv;    // statistical-impossibility fallback
    }
    __syncthreads();
    int lim = min(n, STG);
    for (int l = t; l < lim; l += 256)
        csr[ebase + l] = stage[l];
}

// ---------- B = (x @ W1) * dinv[row] ----------
__global__ __launch_bounds__(256) void gemm1_kernel(const float* __restrict__ x,
                                                    const float* __restrict__ W1,
                                                    const float* __restrict__ dinv,
                                                    float* __restrict__ B) {
    __shared__ float Wl[IN_CH * HID];   // 16 KB
    __shared__ float xs[8 * IN_CH];     // 4 KB
    int tid = threadIdx.x;
    const float4* W4 = (const float4*)W1;
    for (int j = tid; j < IN_CH * HID / 4; j += 256) ((float4*)Wl)[j] = W4[j];
    ((float4*)xs)[tid] = ((const float4*)x)[blockIdx.x * 256 + tid];  // 8 rows
    __syncthreads();
    int r = tid >> 5, c = tid & 31;
    int row = blockIdx.x * 8 + r;
    const float* xr = &xs[r * IN_CH];
    float acc = 0.f;
    #pragma unroll 8
    for (int k = 0; k < IN_CH; ++k) acc += xr[k] * Wl[k * HID + c];
    B[row * HID + c] = acc * dinv[row];
}

// out = relu( (sum_in B[s] + B[d]) * dinv[d] + b1 )     [B already has dinv[s] folded]
__global__ __launch_bounds__(256) void layer1_kernel(const float* __restrict__ B,
                                                     const int* __restrict__ csr,
                                                     const int* __restrict__ row_ptr,
                                                     const float* __restrict__ dinv,
                                                     const float* __restrict__ b1,
                                                     float* __restrict__ out) {
    int tid = threadIdx.x;
    int node = blockIdx.x * 8 + (tid >> 5);
    int c = tid & 31;
    if (node >= N_NODES) return;
    float acc = B[(size_t)node * HID + c];
    int j = row_ptr[node], re = row_ptr[node + 1];
    for (; j < re; ++j) {
        int s = csr[j];
        acc += B[(size_t)s * HID + c];
    }
    out[(size_t)node * HID + c] = fmaxf(acc * dinv[node] + b1[c], 0.f);
}

// B = (in @ W2) * dinv[row]
__global__ __launch_bounds__(256) void gemm2_kernel(const float* __restrict__ in,
                                                    const float* __restrict__ W2,
                                                    const float* __restrict__ dinv,
                                                    float* __restrict__ B) {
    __shared__ float Wl[HID * HID];     // 4 KB
    __shared__ float xs[8 * HID];       // 1 KB
    int tid = threadIdx.x;
    ((float4*)Wl)[tid] = ((const float4*)W2)[tid];        // 1024 floats
    xs[tid] = in[(size_t)blockIdx.x * 256 + tid];         // 8 rows
    __syncthreads();
    int r = tid >> 5, c = tid & 31;
    int row = blockIdx.x * 8 + r;
    float acc = 0.f;
    #pragma unroll
    for (int k = 0; k < HID; ++k) acc += xs[r * HID + k] * Wl[k * HID + c];
    B[(size_t)row * HID + c] = acc * dinv[row];
}

// out = (sum_in B[s] + B[d]) * dinv[d] + b2   (no relu)
__global__ __launch_bounds__(256) void layer2_kernel(const float* __restrict__ B,
                                                     const int* __restrict__ csr,
                                                     const int* __restrict__ row_ptr,
                                                     const float* __restrict__ dinv,
                                                     const float* __restrict__ b2,
                                                     float* __restrict__ out) {
    int tid = threadIdx.x;
    int node = blockIdx.x * 8 + (tid >> 5);
    int c = tid & 31;
    if (node >= N_NODES) return;
    float acc = B[(size_t)node * HID + c];
    int j = row_ptr[node], re = row_ptr[node + 1];
    for (; j < re; ++j) {
        int s = csr[j];
        acc += B[(size_t)s * HID + c];
    }
    out[(size_t)node * HID + c] = acc * dinv[node] + b2[c];
}

// per-graph mean-pool inputs (LDS-staged; no sortedness assumption)
__global__ __launch_bounds__(256) void pool_kernel(const float* __restrict__ h,
                                                   const int* __restrict__ batch,
                                                   float* __restrict__ gsum,
                                                   float* __restrict__ cnt) {
    __shared__ float pool[N_GRAPHS * HID];  // 8 KB
    __shared__ float cntl[N_GRAPHS];
    int tid = threadIdx.x;
    for (int j = tid; j < N_GRAPHS * HID; j += 256) pool[j] = 0.f;
    if (tid < N_GRAPHS) cntl[tid] = 0.f;
    __syncthreads();
    int start = blockIdx.x * POOL_NODES;
    int end = min(start + POOL_NODES, N_NODES);
    int c = tid & 31;
    for (int nb = start + (tid >> 5); nb < end; nb += 8) {
        float v = h[(size_t)nb * HID + c];
        int g = batch[nb];
        if ((unsigned)g < N_GRAPHS) {
            atomicAdd(&pool[g * HID + c], v);
            if (c == 0) atomicAdd(&cntl[g], 1.f);
        }
    }
    __syncthreads();
    for (int j = tid; j < N_GRAPHS * HID; j += 256) atomicAdd(&gsum[j], pool[j]);
    if (tid < N_GRAPHS) atomicAdd(&cnt[tid], cntl[tid]);
}

__global__ void summary_kernel(const float* __restrict__ gsum, const float* __restrict__ cnt,
                               const float* __restrict__ Ws, const float* __restrict__ bs,
                               float* __restrict__ out) {
    int g = blockIdx.x, c = threadIdx.x;
    float inv = 1.f / fmaxf(cnt[g], 1.f);
    float acc = bs[c];
    #pragma unroll
    for (int k = 0; k < HID; ++k)
        acc += gsum[g * HID + k] * inv * Ws[k * HID + c];
    out[g * HID + c] = acc;
}

extern "C" void kernel_launch(void* const* d_in, const int* in_sizes, int n_in,
                              void* d_out, int out_size, void* d_ws, size_t ws_size,
                              hipStream_t stream) {
    const float* x    = (const float*)d_in[0];
    const int* edge   = (const int*)d_in[1];
    const int* src    = edge;
    const int* dst    = edge + N_EDGES;
    const int* batch  = (const int*)d_in[2];
    const float* W1   = (const float*)d_in[3];
    const float* b1   = (const float*)d_in[4];
    const float* W2   = (const float*)d_in[5];
    const float* b2   = (const float*)d_in[6];
    const float* Ws   = (const float*)d_in[7];
    const float* bs   = (const float*)d_in[8];

    float* ws      = (float*)d_ws;
    float* B       = ws + OFF_B;
    int*   H       = (int*)(ws + OFF_B);        // aliases B head; dead before gemm1
    int*   edgepk  = (int*)(ws + OFF_EDGEPK);
    int*   csr     = (int*)(ws + OFF_CSR);
    int*   colT    = (int*)(ws + OFF_COLT);
    int*   binB    = (int*)(ws + OFF_BINB);
    int*   row_ptr = (int*)(ws + OFF_ROWPTR);
    float* dinv    = ws + OFF_DINV;
    float* gsum    = ws + OFF_EDGEPK;           // aliases edgepk head; dead after csr2
    float* cnt     = gsum + N_GRAPHS * HID;

    float* out     = (float*)d_out;
    float* out_sum = out;                    // [64,32]
    float* out_h   = out + N_GRAPHS * HID;   // [100000,32] — also h1 scratch

    // CSR build: hist -> scans -> bin-grouped scatter -> within-bin CSR (+deg/dinv)
    hist_kernel    <<<MGRID, 512, 0, stream>>>(dst, H);
    scanrow_kernel <<<NBIN,  512, 0, stream>>>(H, colT);
    scanbase_kernel<<<1,     512, 0, stream>>>(colT, binB, row_ptr);
    msplit_kernel  <<<MGRID, 512, 0, stream>>>(src, dst, H, binB, edgepk);
    csr2_kernel    <<<NBIN,  256, 0, stream>>>(edgepk, binB, row_ptr, dinv, csr);

    // layer 1
    gemm1_kernel <<<N_NODES / 8, 256, 0, stream>>>(x, W1, dinv, B);
    layer1_kernel<<<N_NODES / 8, 256, 0, stream>>>(B, csr, row_ptr, dinv, b1, out_h);

    // layer 2
    gemm2_kernel <<<N_NODES / 8, 256, 0, stream>>>(out_h, W2, dinv, B);
    layer2_kernel<<<N_NODES / 8, 256, 0, stream>>>(B, csr, row_ptr, dinv, b2, out_h);

    // pooling + summary (gsum aliases edgepk — edgepk dead now)
    hipMemsetAsync(gsum, 0, (N_GRAPHS * HID + N_GRAPHS) * sizeof(float), stream);
    pool_kernel<<<(N_NODES + POOL_NODES - 1) / POOL_NODES, 256, 0, stream>>>(out_h, batch, gsum, cnt);
    summary_kernel<<<N_GRAPHS, HID, 0, stream>>>(gsum, cnt, Ws, bs, out_sum);
}

// Round 8
// 303.129 us; speedup vs baseline: 2.1769x; 1.3786x over previous
//
#include <hip/hip_runtime.h>

#define N_NODES  100000
#define N_EDGES  1600000
#define IN_CH    128
#define HID      32
#define N_GRAPHS 64

#define NBIN   391            // bins of 256 dst nodes: bin = dst >> 8
#define CHUNK  4096           // edges per multisplit block; grid = 391
#define MGRID  391            // ceil(1.6M / 4096)
#define STG    5120           // csr2 per-bin staging capacity

// workspace layout (4-byte element offsets) — total ~26.4 MB
#define OFF_B      0          // float[3,200,000]  scaled features; H[391*391] aliases head
#define OFF_EDGEPK 3200000    // int[1,600,000]    bin-grouped packed edges; gsum/cnt alias after csr2
#define OFF_CSR    4800000    // int[1,600,000]
#define OFF_COLT   6400000    // int[391]
#define OFF_BINB   6400391    // int[392]
#define OFF_ROWPTR 6400784    // int[100,001]
#define OFF_DINV   6500785    // float[100,000]

#define POOL_NODES 1024

// ---------- phase 1: per-(bin, wg) histogram ----------
__global__ __launch_bounds__(512) void hist_kernel(const int* __restrict__ dst,
                                                   int* __restrict__ H) {
    __shared__ int s[512];
    int t = threadIdx.x, wg = blockIdx.x;
    s[t] = 0;
    __syncthreads();
    int e0 = wg * CHUNK, e1 = min(e0 + CHUNK, N_EDGES);
    for (int e = e0 + t; e < e1; e += 512) {
        int d = dst[e];
        if ((unsigned)d < N_NODES) atomicAdd(&s[d >> 8], 1);
    }
    __syncthreads();
    if (t < NBIN) H[t * MGRID + wg] = s[t];
}

// ---------- phase 2a ----------
__global__ __launch_bounds__(512) void scanrow_kernel(int* __restrict__ H,
                                                      int* __restrict__ colT) {
    __shared__ int s[512];
    int t = threadIdx.x, bin = blockIdx.x;
    s[t] = (t < MGRID) ? H[bin * MGRID + t] : 0;
    __syncthreads();
    for (int off = 1; off < 512; off <<= 1) {
        int v = (t >= off) ? s[t - off] : 0;
        __syncthreads();
        if (t >= off) s[t] += v;
        __syncthreads();
    }
    if (t < MGRID) H[bin * MGRID + t] = t ? s[t - 1] : 0;
    if (t == 0) colT[bin] = s[MGRID - 1];
}

// ---------- phase 2b ----------
__global__ __launch_bounds__(512) void scanbase_kernel(const int* __restrict__ colT,
                                                       int* __restrict__ binB,
                                                       int* __restrict__ row_ptr) {
    __shared__ int s[512];
    int t = threadIdx.x;
    s[t] = (t < NBIN) ? colT[t] : 0;
    __syncthreads();
    for (int off = 1; off < 512; off <<= 1) {
        int v = (t >= off) ? s[t - off] : 0;
        __syncthreads();
        if (t >= off) s[t] += v;
        __syncthreads();
    }
    if (t < NBIN) binB[t] = t ? s[t - 1] : 0;
    if (t == 0) { binB[NBIN] = s[NBIN - 1]; row_ptr[N_NODES] = s[NBIN - 1]; }
}

// ---------- phase 3: bin-grouped scatter, LDS-staged coalesced flush ----------
__global__ __launch_bounds__(512) void msplit_kernel(const int* __restrict__ src,
                                                     const int* __restrict__ dst,
                                                     const int* __restrict__ H,
                                                     const int* __restrict__ binB,
                                                     int* __restrict__ edgepk) {
    __shared__ int s[512];
    __shared__ int cur[NBIN];
    __shared__ int gb[NBIN];
    __shared__ int stage[CHUNK];
    __shared__ int gof[CHUNK];
    int t = threadIdx.x, wg = blockIdx.x;
    s[t] = 0;
    __syncthreads();
    int e0 = wg * CHUNK, e1 = min(e0 + CHUNK, N_EDGES);
    for (int e = e0 + t; e < e1; e += 512) {
        int d = dst[e];
        if ((unsigned)d < N_NODES) atomicAdd(&s[d >> 8], 1);
    }
    __syncthreads();
    for (int off = 1; off < 512; off <<= 1) {
        int v = (t >= off) ? s[t - off] : 0;
        __syncthreads();
        if (t >= off) s[t] += v;
        __syncthreads();
    }
    if (t < NBIN) {
        int lo = t ? s[t - 1] : 0;
        cur[t] = lo;
        gb[t] = binB[t] + H[t * MGRID + wg] - lo;
    }
    __syncthreads();
    for (int e = e0 + t; e < e1; e += 512) {
        int d = dst[e];
        if ((unsigned)d < N_NODES) {
            int b = d >> 8;
            int p = atomicAdd(&cur[b], 1);
            stage[p] = (src[e] << 8) | (d & 255);
            gof[p] = gb[b];
        }
    }
    __syncthreads();
    int total = s[511];
    for (int p = t; p < total; p += 512)
        edgepk[gof[p] + p] = stage[p];
}

// ---------- phase 4: within-bin reorder -> CSR + dinv/row_ptr ----------
__global__ __launch_bounds__(256) void csr2_kernel(const int* __restrict__ edgepk,
                                                   const int* __restrict__ binB,
                                                   int* __restrict__ row_ptr,
                                                   float* __restrict__ dinv,
                                                   int* __restrict__ csr) {
    __shared__ int cnt[256], s[256], cur[256];
    __shared__ int stage[STG];
    int t = threadIdx.x, bin = blockIdx.x;
    int ebase = binB[bin], eend = binB[bin + 1];
    int n = eend - ebase;
    cnt[t] = 0;
    __syncthreads();
    for (int p = ebase + t; p < eend; p += 256)
        atomicAdd(&cnt[edgepk[p] & 255], 1);
    __syncthreads();
    s[t] = cnt[t];
    __syncthreads();
    for (int off = 1; off < 256; off <<= 1) {
        int v = (t >= off) ? s[t - off] : 0;
        __syncthreads();
        if (t >= off) s[t] += v;
        __syncthreads();
    }
    int excl = t ? s[t - 1] : 0;
    int node = (bin << 8) + t;
    if (node < N_NODES) {
        dinv[node] = rsqrtf((float)(cnt[t] + 1));
        row_ptr[node] = ebase + excl;
    }
    cur[t] = excl;
    __syncthreads();
    for (int p = ebase + t; p < eend; p += 256) {
        int w = edgepk[p];
        int l = atomicAdd(&cur[w & 255], 1);
        int sv = w >> 8;
        if (l < STG) stage[l] = sv;
        else csr[ebase + l] = sv;
    }
    __syncthreads();
    int lim = min(n, STG);
    for (int l = t; l < lim; l += 256)
        csr[ebase + l] = stage[l];
}

// ---------- B = (x @ W1) * dinv[row], register-tiled (4 ch/thread) ----------
#define XS1 132               // 128 + 4 pad: banks (4r+k)%32 distinct across 8 r's; 16B-aligned rows
__global__ __launch_bounds__(256) void gemm1_kernel(const float* __restrict__ x,
                                                    const float* __restrict__ W1,
                                                    const float* __restrict__ dinv,
                                                    float* __restrict__ B) {
    __shared__ float Wl[IN_CH * HID];   // 16 KB
    __shared__ float xs[32 * XS1];      // 16.9 KB
    int tid = threadIdx.x;
    for (int j = tid; j < IN_CH * HID / 4; j += 256)
        ((float4*)Wl)[j] = ((const float4*)W1)[j];
    int row0 = blockIdx.x * 32;         // 100000 % 32 == 0
    const float4* x4 = (const float4*)(x + (size_t)row0 * IN_CH);
    for (int j = tid; j < 32 * IN_CH / 4; j += 256) {
        int r = j >> 5, k4 = j & 31;
        ((float4*)&xs[r * XS1])[k4] = x4[j];
    }
    __syncthreads();
    int r = tid >> 3, cg = (tid & 7) * 4;
    const float* xr = &xs[r * XS1];
    float4 acc = {0.f, 0.f, 0.f, 0.f};
    #pragma unroll 8
    for (int k = 0; k < IN_CH; ++k) {
        float xv = xr[k];
        float4 w = *(const float4*)&Wl[k * HID + cg];
        acc.x += xv * w.x; acc.y += xv * w.y; acc.z += xv * w.z; acc.w += xv * w.w;
    }
    int row = row0 + r;
    float dv = dinv[row];
    acc.x *= dv; acc.y *= dv; acc.z *= dv; acc.w *= dv;
    *(float4*)&B[(size_t)row * HID + cg] = acc;
}

// ---------- B = (in @ W2) * dinv[row], register-tiled ----------
#define XS2 36                // 32 + 4 pad
__global__ __launch_bounds__(256) void gemm2_kernel(const float* __restrict__ in,
                                                    const float* __restrict__ W2,
                                                    const float* __restrict__ dinv,
                                                    float* __restrict__ B) {
    __shared__ float Wl[HID * HID];     // 4 KB
    __shared__ float xs[32 * XS2];      // 4.6 KB
    int tid = threadIdx.x;
    ((float4*)Wl)[tid] = ((const float4*)W2)[tid];   // 256 float4 = 1024 floats
    int row0 = blockIdx.x * 32;
    const float4* in4 = (const float4*)(in + (size_t)row0 * HID);
    {   // 32 rows * 32 ch = 256 float4, one per thread
        int r = tid >> 3, k4 = tid & 7;
        ((float4*)&xs[r * XS2])[k4] = in4[tid];
    }
    __syncthreads();
    int r = tid >> 3, cg = (tid & 7) * 4;
    const float* xr = &xs[r * XS2];
    float4 acc = {0.f, 0.f, 0.f, 0.f};
    #pragma unroll
    for (int k = 0; k < HID; ++k) {
        float xv = xr[k];
        float4 w = *(const float4*)&Wl[k * HID + cg];
        acc.x += xv * w.x; acc.y += xv * w.y; acc.z += xv * w.z; acc.w += xv * w.w;
    }
    int row = row0 + r;
    float dv = dinv[row];
    acc.x *= dv; acc.y *= dv; acc.z *= dv; acc.w *= dv;
    *(float4*)&B[(size_t)row * HID + cg] = acc;
}

// ---------- gather layer: out = (sum_in B[s] + B[d]) * dinv[d] + bias, opt relu ----------
// 8-wide unrolled gather for memory-level parallelism (8 independent B-loads in flight)
__global__ __launch_bounds__(256) void layer_kernel(const float* __restrict__ B,
                                                    const int* __restrict__ csr,
                                                    const int* __restrict__ row_ptr,
                                                    const float* __restrict__ dinv,
                                                    const float* __restrict__ bias,
                                                    float* __restrict__ out,
                                                    int relu) {
    int tid = threadIdx.x;
    int node = blockIdx.x * 8 + (tid >> 5);
    int c = tid & 31;
    float acc = B[(size_t)node * HID + c];
    int j = row_ptr[node], re = row_ptr[node + 1];
    for (; j + 8 <= re; j += 8) {
        int s0 = csr[j + 0], s1 = csr[j + 1], s2 = csr[j + 2], s3 = csr[j + 3];
        int s4 = csr[j + 4], s5 = csr[j + 5], s6 = csr[j + 6], s7 = csr[j + 7];
        float v0 = B[(size_t)s0 * HID + c], v1 = B[(size_t)s1 * HID + c];
        float v2 = B[(size_t)s2 * HID + c], v3 = B[(size_t)s3 * HID + c];
        float v4 = B[(size_t)s4 * HID + c], v5 = B[(size_t)s5 * HID + c];
        float v6 = B[(size_t)s6 * HID + c], v7 = B[(size_t)s7 * HID + c];
        acc += ((v0 + v1) + (v2 + v3)) + ((v4 + v5) + (v6 + v7));
    }
    if (j + 4 <= re) {
        int s0 = csr[j], s1 = csr[j + 1], s2 = csr[j + 2], s3 = csr[j + 3];
        float v0 = B[(size_t)s0 * HID + c], v1 = B[(size_t)s1 * HID + c];
        float v2 = B[(size_t)s2 * HID + c], v3 = B[(size_t)s3 * HID + c];
        acc += (v0 + v1) + (v2 + v3);
        j += 4;
    }
    for (; j < re; ++j) acc += B[(size_t)csr[j] * HID + c];
    float r = acc * dinv[node] + bias[c];
    out[(size_t)node * HID + c] = relu ? fmaxf(r, 0.f) : r;
}

// ---------- per-graph mean-pool ----------
__global__ __launch_bounds__(256) void pool_kernel(const float* __restrict__ h,
                                                   const int* __restrict__ batch,
                                                   float* __restrict__ gsum,
                                                   float* __restrict__ cnt) {
    __shared__ float pool[N_GRAPHS * HID];
    __shared__ float cntl[N_GRAPHS];
    int tid = threadIdx.x;
    for (int j = tid; j < N_GRAPHS * HID; j += 256) pool[j] = 0.f;
    if (tid < N_GRAPHS) cntl[tid] = 0.f;
    __syncthreads();
    int start = blockIdx.x * POOL_NODES;
    int end = min(start + POOL_NODES, N_NODES);
    int c = tid & 31;
    for (int nb = start + (tid >> 5); nb < end; nb += 8) {
        float v = h[(size_t)nb * HID + c];
        int g = batch[nb];
        if ((unsigned)g < N_GRAPHS) {
            atomicAdd(&pool[g * HID + c], v);
            if (c == 0) atomicAdd(&cntl[g], 1.f);
        }
    }
    __syncthreads();
    for (int j = tid; j < N_GRAPHS * HID; j += 256) atomicAdd(&gsum[j], pool[j]);
    if (tid < N_GRAPHS) atomicAdd(&cnt[tid], cntl[tid]);
}

__global__ void summary_kernel(const float* __restrict__ gsum, const float* __restrict__ cnt,
                               const float* __restrict__ Ws, const float* __restrict__ bs,
                               float* __restrict__ out) {
    int g = blockIdx.x, c = threadIdx.x;
    float inv = 1.f / fmaxf(cnt[g], 1.f);
    float acc = bs[c];
    #pragma unroll
    for (int k = 0; k < HID; ++k)
        acc += gsum[g * HID + k] * inv * Ws[k * HID + c];
    out[g * HID + c] = acc;
}

extern "C" void kernel_launch(void* const* d_in, const int* in_sizes, int n_in,
                              void* d_out, int out_size, void* d_ws, size_t ws_size,
                              hipStream_t stream) {
    const float* x    = (const float*)d_in[0];
    const int* edge   = (const int*)d_in[1];
    const int* src    = edge;
    const int* dst    = edge + N_EDGES;
    const int* batch  = (const int*)d_in[2];
    const float* W1   = (const float*)d_in[3];
    const float* b1   = (const float*)d_in[4];
    const float* W2   = (const float*)d_in[5];
    const float* b2   = (const float*)d_in[6];
    const float* Ws   = (const float*)d_in[7];
    const float* bs   = (const float*)d_in[8];

    float* ws      = (float*)d_ws;
    float* B       = ws + OFF_B;
    int*   H       = (int*)(ws + OFF_B);
    int*   edgepk  = (int*)(ws + OFF_EDGEPK);
    int*   csr     = (int*)(ws + OFF_CSR);
    int*   colT    = (int*)(ws + OFF_COLT);
    int*   binB    = (int*)(ws + OFF_BINB);
    int*   row_ptr = (int*)(ws + OFF_ROWPTR);
    float* dinv    = ws + OFF_DINV;
    float* gsum    = ws + OFF_EDGEPK;           // aliases edgepk (dead after csr2)
    float* cnt     = gsum + N_GRAPHS * HID;

    float* out     = (float*)d_out;
    float* out_sum = out;
    float* out_h   = out + N_GRAPHS * HID;

    // CSR build
    hist_kernel    <<<MGRID, 512, 0, stream>>>(dst, H);
    scanrow_kernel <<<NBIN,  512, 0, stream>>>(H, colT);
    scanbase_kernel<<<1,     512, 0, stream>>>(colT, binB, row_ptr);
    msplit_kernel  <<<MGRID, 512, 0, stream>>>(src, dst, H, binB, edgepk);
    csr2_kernel    <<<NBIN,  256, 0, stream>>>(edgepk, binB, row_ptr, dinv, csr);

    // layer 1
    gemm1_kernel<<<N_NODES / 32, 256, 0, stream>>>(x, W1, dinv, B);
    layer_kernel<<<N_NODES / 8, 256, 0, stream>>>(B, csr, row_ptr, dinv, b1, out_h, 1);

    // layer 2
    gemm2_kernel<<<N_NODES / 32, 256, 0, stream>>>(out_h, W2, dinv, B);
    layer_kernel<<<N_NODES / 8, 256, 0, stream>>>(B, csr, row_ptr, dinv, b2, out_h, 0);

    // pooling + summary
    hipMemsetAsync(gsum, 0, (N_GRAPHS * HID + N_GRAPHS) * sizeof(float), stream);
    pool_kernel<<<(N_NODES + POOL_NODES - 1) / POOL_NODES, 256, 0, stream>>>(out_h, batch, gsum, cnt);
    summary_kernel<<<N_GRAPHS, HID, 0, stream>>>(gsum, cnt, Ws, bs, out_sum);
}

// Round 9
// 257.410 us; speedup vs baseline: 2.5635x; 1.1776x over previous
//
#include <hip/hip_runtime.h>

#define N_NODES  100000
#define N_EDGES  1600000
#define IN_CH    128
#define HID      32
#define N_GRAPHS 64

#define NBIN   391            // bins of 256 dst nodes: bin = dst >> 8
#define CHUNK  4096           // edges per multisplit block; grid = 391
#define MGRID  391            // ceil(1.6M / 4096)
#define STG    5120           // csr2 per-bin staging capacity

// workspace layout (4-byte element offsets) — total ~26.4 MB
#define OFF_B      0          // float[3,200,000]  scaled features; H[391*391] aliases head
#define OFF_EDGEPK 3200000    // int[1,600,000]    bin-grouped packed edges; gsum/cnt alias after csr2
#define OFF_CSR    4800000    // int[1,600,000]
#define OFF_COLT   6400000    // int[391]
#define OFF_BINB   6400391    // int[392]
#define OFF_ROWPTR 6400784    // int[100,001]
#define OFF_DINV   6500785    // float[100,000]

// ---------- phase 1: per-(bin, wg) histogram ----------
__global__ __launch_bounds__(512) void hist_kernel(const int* __restrict__ dst,
                                                   int* __restrict__ H) {
    __shared__ int s[512];
    int t = threadIdx.x, wg = blockIdx.x;
    s[t] = 0;
    __syncthreads();
    int e0 = wg * CHUNK, e1 = min(e0 + CHUNK, N_EDGES);
    for (int e = e0 + t; e < e1; e += 512) {
        int d = dst[e];
        if ((unsigned)d < N_NODES) atomicAdd(&s[d >> 8], 1);
    }
    __syncthreads();
    if (t < NBIN) H[t * MGRID + wg] = s[t];
}

// ---------- phase 2a ----------
__global__ __launch_bounds__(512) void scanrow_kernel(int* __restrict__ H,
                                                      int* __restrict__ colT) {
    __shared__ int s[512];
    int t = threadIdx.x, bin = blockIdx.x;
    s[t] = (t < MGRID) ? H[bin * MGRID + t] : 0;
    __syncthreads();
    for (int off = 1; off < 512; off <<= 1) {
        int v = (t >= off) ? s[t - off] : 0;
        __syncthreads();
        if (t >= off) s[t] += v;
        __syncthreads();
    }
    if (t < MGRID) H[bin * MGRID + t] = t ? s[t - 1] : 0;
    if (t == 0) colT[bin] = s[MGRID - 1];
}

// ---------- phase 2b ----------
__global__ __launch_bounds__(512) void scanbase_kernel(const int* __restrict__ colT,
                                                       int* __restrict__ binB,
                                                       int* __restrict__ row_ptr) {
    __shared__ int s[512];
    int t = threadIdx.x;
    s[t] = (t < NBIN) ? colT[t] : 0;
    __syncthreads();
    for (int off = 1; off < 512; off <<= 1) {
        int v = (t >= off) ? s[t - off] : 0;
        __syncthreads();
        if (t >= off) s[t] += v;
        __syncthreads();
    }
    if (t < NBIN) binB[t] = t ? s[t - 1] : 0;
    if (t == 0) { binB[NBIN] = s[NBIN - 1]; row_ptr[N_NODES] = s[NBIN - 1]; }
}

// ---------- phase 3: bin-grouped scatter, LDS-staged coalesced flush ----------
__global__ __launch_bounds__(512) void msplit_kernel(const int* __restrict__ src,
                                                     const int* __restrict__ dst,
                                                     const int* __restrict__ H,
                                                     const int* __restrict__ binB,
                                                     int* __restrict__ edgepk) {
    __shared__ int s[512];
    __shared__ int cur[NBIN];
    __shared__ int gb[NBIN];
    __shared__ int stage[CHUNK];
    __shared__ int gof[CHUNK];
    int t = threadIdx.x, wg = blockIdx.x;
    s[t] = 0;
    __syncthreads();
    int e0 = wg * CHUNK, e1 = min(e0 + CHUNK, N_EDGES);
    for (int e = e0 + t; e < e1; e += 512) {
        int d = dst[e];
        if ((unsigned)d < N_NODES) atomicAdd(&s[d >> 8], 1);
    }
    __syncthreads();
    for (int off = 1; off < 512; off <<= 1) {
        int v = (t >= off) ? s[t - off] : 0;
        __syncthreads();
        if (t >= off) s[t] += v;
        __syncthreads();
    }
    if (t < NBIN) {
        int lo = t ? s[t - 1] : 0;
        cur[t] = lo;
        gb[t] = binB[t] + H[t * MGRID + wg] - lo;
    }
    __syncthreads();
    for (int e = e0 + t; e < e1; e += 512) {
        int d = dst[e];
        if ((unsigned)d < N_NODES) {
            int b = d >> 8;
            int p = atomicAdd(&cur[b], 1);
            stage[p] = (src[e] << 8) | (d & 255);
            gof[p] = gb[b];
        }
    }
    __syncthreads();
    int total = s[511];
    for (int p = t; p < total; p += 512)
        edgepk[gof[p] + p] = stage[p];
}

// ---------- phase 4: within-bin reorder -> CSR + dinv/row_ptr ----------
__global__ __launch_bounds__(256) void csr2_kernel(const int* __restrict__ edgepk,
                                                   const int* __restrict__ binB,
                                                   int* __restrict__ row_ptr,
                                                   float* __restrict__ dinv,
                                                   int* __restrict__ csr) {
    __shared__ int cnt[256], s[256], cur[256];
    __shared__ int stage[STG];
    int t = threadIdx.x, bin = blockIdx.x;
    int ebase = binB[bin], eend = binB[bin + 1];
    int n = eend - ebase;
    cnt[t] = 0;
    __syncthreads();
    for (int p = ebase + t; p < eend; p += 256)
        atomicAdd(&cnt[edgepk[p] & 255], 1);
    __syncthreads();
    s[t] = cnt[t];
    __syncthreads();
    for (int off = 1; off < 256; off <<= 1) {
        int v = (t >= off) ? s[t - off] : 0;
        __syncthreads();
        if (t >= off) s[t] += v;
        __syncthreads();
    }
    int excl = t ? s[t - 1] : 0;
    int node = (bin << 8) + t;
    if (node < N_NODES) {
        dinv[node] = rsqrtf((float)(cnt[t] + 1));
        row_ptr[node] = ebase + excl;
    }
    cur[t] = excl;
    __syncthreads();
    for (int p = ebase + t; p < eend; p += 256) {
        int w = edgepk[p];
        int l = atomicAdd(&cur[w & 255], 1);
        int sv = w >> 8;
        if (l < STG) stage[l] = sv;
        else csr[ebase + l] = sv;
    }
    __syncthreads();
    int lim = min(n, STG);
    for (int l = t; l < lim; l += 256)
        csr[ebase + l] = stage[l];
}

// ---------- B = (x @ W1) * dinv[row], register-tiled (4 ch/thread) ----------
#define XS1 132               // 128 + 4 pad
__global__ __launch_bounds__(256) void gemm1_kernel(const float* __restrict__ x,
                                                    const float* __restrict__ W1,
                                                    const float* __restrict__ dinv,
                                                    float* __restrict__ B) {
    __shared__ float Wl[IN_CH * HID];   // 16 KB
    __shared__ float xs[32 * XS1];      // 16.9 KB
    int tid = threadIdx.x;
    for (int j = tid; j < IN_CH * HID / 4; j += 256)
        ((float4*)Wl)[j] = ((const float4*)W1)[j];
    int row0 = blockIdx.x * 32;         // 100000 % 32 == 0
    const float4* x4 = (const float4*)(x + (size_t)row0 * IN_CH);
    for (int j = tid; j < 32 * IN_CH / 4; j += 256) {
        int r = j >> 5, k4 = j & 31;
        ((float4*)&xs[r * XS1])[k4] = x4[j];
    }
    __syncthreads();
    int r = tid >> 3, cg = (tid & 7) * 4;
    const float* xr = &xs[r * XS1];
    float4 acc = {0.f, 0.f, 0.f, 0.f};
    #pragma unroll 8
    for (int k = 0; k < IN_CH; ++k) {
        float xv = xr[k];
        float4 w = *(const float4*)&Wl[k * HID + cg];
        acc.x += xv * w.x; acc.y += xv * w.y; acc.z += xv * w.z; acc.w += xv * w.w;
    }
    int row = row0 + r;
    float dv = dinv[row];
    acc.x *= dv; acc.y *= dv; acc.z *= dv; acc.w *= dv;
    *(float4*)&B[(size_t)row * HID + cg] = acc;
}

// ---------- B = (in @ W2) * dinv[row], register-tiled ----------
#define XS2 36                // 32 + 4 pad
__global__ __launch_bounds__(256) void gemm2_kernel(const float* __restrict__ in,
                                                    const float* __restrict__ W2,
                                                    const float* __restrict__ dinv,
                                                    float* __restrict__ B) {
    __shared__ float Wl[HID * HID];     // 4 KB
    __shared__ float xs[32 * XS2];      // 4.6 KB
    int tid = threadIdx.x;
    ((float4*)Wl)[tid] = ((const float4*)W2)[tid];
    int row0 = blockIdx.x * 32;
    const float4* in4 = (const float4*)(in + (size_t)row0 * HID);
    {
        int r = tid >> 3, k4 = tid & 7;
        ((float4*)&xs[r * XS2])[k4] = in4[tid];
    }
    __syncthreads();
    int r = tid >> 3, cg = (tid & 7) * 4;
    const float* xr = &xs[r * XS2];
    float4 acc = {0.f, 0.f, 0.f, 0.f};
    #pragma unroll
    for (int k = 0; k < HID; ++k) {
        float xv = xr[k];
        float4 w = *(const float4*)&Wl[k * HID + cg];
        acc.x += xv * w.x; acc.y += xv * w.y; acc.z += xv * w.z; acc.w += xv * w.w;
    }
    int row = row0 + r;
    float dv = dinv[row];
    acc.x *= dv; acc.y *= dv; acc.z *= dv; acc.w *= dv;
    *(float4*)&B[(size_t)row * HID + cg] = acc;
}

// ---------- gather layer (8-wide MLP unroll) ----------
__global__ __launch_bounds__(256) void layer_kernel(const float* __restrict__ B,
                                                    const int* __restrict__ csr,
                                                    const int* __restrict__ row_ptr,
                                                    const float* __restrict__ dinv,
                                                    const float* __restrict__ bias,
                                                    float* __restrict__ out,
                                                    int relu) {
    int tid = threadIdx.x;
    int node = blockIdx.x * 8 + (tid >> 5);
    int c = tid & 31;
    float acc = B[(size_t)node * HID + c];
    int j = row_ptr[node], re = row_ptr[node + 1];
    for (; j + 8 <= re; j += 8) {
        int s0 = csr[j + 0], s1 = csr[j + 1], s2 = csr[j + 2], s3 = csr[j + 3];
        int s4 = csr[j + 4], s5 = csr[j + 5], s6 = csr[j + 6], s7 = csr[j + 7];
        float v0 = B[(size_t)s0 * HID + c], v1 = B[(size_t)s1 * HID + c];
        float v2 = B[(size_t)s2 * HID + c], v3 = B[(size_t)s3 * HID + c];
        float v4 = B[(size_t)s4 * HID + c], v5 = B[(size_t)s5 * HID + c];
        float v6 = B[(size_t)s6 * HID + c], v7 = B[(size_t)s7 * HID + c];
        acc += ((v0 + v1) + (v2 + v3)) + ((v4 + v5) + (v6 + v7));
    }
    if (j + 4 <= re) {
        int s0 = csr[j], s1 = csr[j + 1], s2 = csr[j + 2], s3 = csr[j + 3];
        float v0 = B[(size_t)s0 * HID + c], v1 = B[(size_t)s1 * HID + c];
        float v2 = B[(size_t)s2 * HID + c], v3 = B[(size_t)s3 * HID + c];
        acc += (v0 + v1) + (v2 + v3);
        j += 4;
    }
    for (; j < re; ++j) acc += B[(size_t)csr[j] * HID + c];
    float r = acc * dinv[node] + bias[c];
    out[(size_t)node * HID + c] = relu ? fmaxf(r, 0.f) : r;
}

// ---------- per-graph mean-pool: register run-accumulation + span flush ----------
__global__ __launch_bounds__(256) void pool_kernel(const float* __restrict__ h,
                                                   const int* __restrict__ batch,
                                                   float* __restrict__ gsum,
                                                   float* __restrict__ cnt) {
    __shared__ float pool[N_GRAPHS * HID];  // 8 KB
    __shared__ float cntl[N_GRAPHS];
    __shared__ int gmin, gmax;
    int t = threadIdx.x;
    for (int j = t; j < N_GRAPHS * HID; j += 256) pool[j] = 0.f;
    if (t < N_GRAPHS) cntl[t] = 0.f;
    if (t == 0) { gmin = N_GRAPHS; gmax = -1; }
    __syncthreads();
    int start = blockIdx.x * 256;
    int end = min(start + 256, N_NODES);
    int c = t & 31;
    float racc = 0.f;       // register run accumulator (LDS touched only on run boundary)
    int rg = -1, rcnt = 0;
    for (int nb = start + (t >> 5); nb < end; nb += 8) {
        float v = h[(size_t)nb * HID + c];
        int g = batch[nb];
        if (g != rg) {
            if ((unsigned)rg < N_GRAPHS) {
                atomicAdd(&pool[rg * HID + c], racc);
                if (c == 0) {
                    atomicAdd(&cntl[rg], (float)rcnt);
                    atomicMin(&gmin, rg); atomicMax(&gmax, rg);
                }
            }
            rg = g; racc = v; rcnt = 1;
        } else { racc += v; ++rcnt; }
    }
    if ((unsigned)rg < N_GRAPHS) {
        atomicAdd(&pool[rg * HID + c], racc);
        if (c == 0) {
            atomicAdd(&cntl[rg], (float)rcnt);
            atomicMin(&gmin, rg); atomicMax(&gmax, rg);
        }
    }
    __syncthreads();
    int lo = gmin, hi = gmax;
    if (hi >= lo) {
        int span = (hi - lo + 1) * HID;
        for (int j = t; j < span; j += 256)
            atomicAdd(&gsum[lo * HID + j], pool[lo * HID + j]);
        for (int j = t; j <= hi - lo; j += 256)
            atomicAdd(&cnt[lo + j], cntl[lo + j]);
    }
}

__global__ void summary_kernel(const float* __restrict__ gsum, const float* __restrict__ cnt,
                               const float* __restrict__ Ws, const float* __restrict__ bs,
                               float* __restrict__ out) {
    int g = blockIdx.x, c = threadIdx.x;
    float inv = 1.f / fmaxf(cnt[g], 1.f);
    float acc = bs[c];
    #pragma unroll
    for (int k = 0; k < HID; ++k)
        acc += gsum[g * HID + k] * inv * Ws[k * HID + c];
    out[g * HID + c] = acc;
}

extern "C" void kernel_launch(void* const* d_in, const int* in_sizes, int n_in,
                              void* d_out, int out_size, void* d_ws, size_t ws_size,
                              hipStream_t stream) {
    const float* x    = (const float*)d_in[0];
    const int* edge   = (const int*)d_in[1];
    const int* src    = edge;
    const int* dst    = edge + N_EDGES;
    const int* batch  = (const int*)d_in[2];
    const float* W1   = (const float*)d_in[3];
    const float* b1   = (const float*)d_in[4];
    const float* W2   = (const float*)d_in[5];
    const float* b2   = (const float*)d_in[6];
    const float* Ws   = (const float*)d_in[7];
    const float* bs   = (const float*)d_in[8];

    float* ws      = (float*)d_ws;
    float* B       = ws + OFF_B;
    int*   H       = (int*)(ws + OFF_B);
    int*   edgepk  = (int*)(ws + OFF_EDGEPK);
    int*   csr     = (int*)(ws + OFF_CSR);
    int*   colT    = (int*)(ws + OFF_COLT);
    int*   binB    = (int*)(ws + OFF_BINB);
    int*   row_ptr = (int*)(ws + OFF_ROWPTR);
    float* dinv    = ws + OFF_DINV;
    float* gsum    = ws + OFF_EDGEPK;           // aliases edgepk (dead after csr2)
    float* cnt     = gsum + N_GRAPHS * HID;

    float* out     = (float*)d_out;
    float* out_sum = out;
    float* out_h   = out + N_GRAPHS * HID;

    // CSR build
    hist_kernel    <<<MGRID, 512, 0, stream>>>(dst, H);
    scanrow_kernel <<<NBIN,  512, 0, stream>>>(H, colT);
    scanbase_kernel<<<1,     512, 0, stream>>>(colT, binB, row_ptr);
    msplit_kernel  <<<MGRID, 512, 0, stream>>>(src, dst, H, binB, edgepk);
    csr2_kernel    <<<NBIN,  256, 0, stream>>>(edgepk, binB, row_ptr, dinv, csr);

    // layer 1
    gemm1_kernel<<<N_NODES / 32, 256, 0, stream>>>(x, W1, dinv, B);
    layer_kernel<<<N_NODES / 8, 256, 0, stream>>>(B, csr, row_ptr, dinv, b1, out_h, 1);

    // layer 2
    gemm2_kernel<<<N_NODES / 32, 256, 0, stream>>>(out_h, W2, dinv, B);
    layer_kernel<<<N_NODES / 8, 256, 0, stream>>>(B, csr, row_ptr, dinv, b2, out_h, 0);

    // pooling + summary
    hipMemsetAsync(gsum, 0, (N_GRAPHS * HID + N_GRAPHS) * sizeof(float), stream);
    pool_kernel<<<NBIN, 256, 0, stream>>>(out_h, batch, gsum, cnt);
    summary_kernel<<<N_GRAPHS, HID, 0, stream>>>(gsum, cnt, Ws, bs, out_sum);
}

// Round 10
// 235.929 us; speedup vs baseline: 2.7969x; 1.0911x over previous
//
#include <hip/hip_runtime.h>

#define N_NODES  100000
#define N_EDGES  1600000
#define IN_CH    128
#define HID      32
#define N_GRAPHS 64

#define NBIN   391            // bins of 256 dst nodes: bin = dst >> 8
#define CHUNK  4096           // edges per multisplit block; grid = 391
#define MGRID  391            // ceil(1.6M / 4096)
#define STG    5120           // csr2 per-bin staging capacity

// workspace layout (4-byte element offsets) — total ~26.4 MB
#define OFF_B      0          // bf16[3,200,000] packed as uint[1,600,000]; H[391*391] aliases head
#define OFF_EDGEPK 3200000    // int[1,600,000]; gsum/cnt alias after csr2
#define OFF_CSR    4800000    // int[1,600,000]
#define OFF_COLT   6400000    // int[391]
#define OFF_BINB   6400391    // int[392]
#define OFF_ROWPTR 6400784    // int[100,001]
#define OFF_DINV   6500785    // float[100,000]

// bf16 pack (RNE) / unpack helpers
__device__ __forceinline__ unsigned bfr(float f) {
    unsigned u = __float_as_uint(f);
    u += 0x7fffu + ((u >> 16) & 1u);
    return u >> 16;
}
__device__ __forceinline__ float bflo(unsigned w) { return __uint_as_float(w << 16); }
__device__ __forceinline__ float bfhi(unsigned w) { return __uint_as_float(w & 0xffff0000u); }

// ---------- phase 1: per-(bin, wg) histogram ----------
__global__ __launch_bounds__(512) void hist_kernel(const int* __restrict__ dst,
                                                   int* __restrict__ H) {
    __shared__ int s[512];
    int t = threadIdx.x, wg = blockIdx.x;
    s[t] = 0;
    __syncthreads();
    int e0 = wg * CHUNK, e1 = min(e0 + CHUNK, N_EDGES);
    for (int e = e0 + t; e < e1; e += 512) {
        int d = dst[e];
        if ((unsigned)d < N_NODES) atomicAdd(&s[d >> 8], 1);
    }
    __syncthreads();
    if (t < NBIN) H[t * MGRID + wg] = s[t];
}

// ---------- phase 2a ----------
__global__ __launch_bounds__(512) void scanrow_kernel(int* __restrict__ H,
                                                      int* __restrict__ colT) {
    __shared__ int s[512];
    int t = threadIdx.x, bin = blockIdx.x;
    s[t] = (t < MGRID) ? H[bin * MGRID + t] : 0;
    __syncthreads();
    for (int off = 1; off < 512; off <<= 1) {
        int v = (t >= off) ? s[t - off] : 0;
        __syncthreads();
        if (t >= off) s[t] += v;
        __syncthreads();
    }
    if (t < MGRID) H[bin * MGRID + t] = t ? s[t - 1] : 0;
    if (t == 0) colT[bin] = s[MGRID - 1];
}

// ---------- phase 2b ----------
__global__ __launch_bounds__(512) void scanbase_kernel(const int* __restrict__ colT,
                                                       int* __restrict__ binB,
                                                       int* __restrict__ row_ptr) {
    __shared__ int s[512];
    int t = threadIdx.x;
    s[t] = (t < NBIN) ? colT[t] : 0;
    __syncthreads();
    for (int off = 1; off < 512; off <<= 1) {
        int v = (t >= off) ? s[t - off] : 0;
        __syncthreads();
        if (t >= off) s[t] += v;
        __syncthreads();
    }
    if (t < NBIN) binB[t] = t ? s[t - 1] : 0;
    if (t == 0) { binB[NBIN] = s[NBIN - 1]; row_ptr[N_NODES] = s[NBIN - 1]; }
}

// ---------- phase 3: bin-grouped scatter, LDS-staged coalesced flush ----------
__global__ __launch_bounds__(512) void msplit_kernel(const int* __restrict__ src,
                                                     const int* __restrict__ dst,
                                                     const int* __restrict__ H,
                                                     const int* __restrict__ binB,
                                                     int* __restrict__ edgepk) {
    __shared__ int s[512];
    __shared__ int cur[NBIN];
    __shared__ int gb[NBIN];
    __shared__ int stage[CHUNK];
    __shared__ int gof[CHUNK];
    int t = threadIdx.x, wg = blockIdx.x;
    s[t] = 0;
    __syncthreads();
    int e0 = wg * CHUNK, e1 = min(e0 + CHUNK, N_EDGES);
    for (int e = e0 + t; e < e1; e += 512) {
        int d = dst[e];
        if ((unsigned)d < N_NODES) atomicAdd(&s[d >> 8], 1);
    }
    __syncthreads();
    for (int off = 1; off < 512; off <<= 1) {
        int v = (t >= off) ? s[t - off] : 0;
        __syncthreads();
        if (t >= off) s[t] += v;
        __syncthreads();
    }
    if (t < NBIN) {
        int lo = t ? s[t - 1] : 0;
        cur[t] = lo;
        gb[t] = binB[t] + H[t * MGRID + wg] - lo;
    }
    __syncthreads();
    for (int e = e0 + t; e < e1; e += 512) {
        int d = dst[e];
        if ((unsigned)d < N_NODES) {
            int b = d >> 8;
            int p = atomicAdd(&cur[b], 1);
            stage[p] = (src[e] << 8) | (d & 255);
            gof[p] = gb[b];
        }
    }
    __syncthreads();
    int total = s[511];
    for (int p = t; p < total; p += 512)
        edgepk[gof[p] + p] = stage[p];
}

// ---------- phase 4: within-bin reorder -> CSR + dinv/row_ptr ----------
__global__ __launch_bounds__(256) void csr2_kernel(const int* __restrict__ edgepk,
                                                   const int* __restrict__ binB,
                                                   int* __restrict__ row_ptr,
                                                   float* __restrict__ dinv,
                                                   int* __restrict__ csr) {
    __shared__ int cnt[256], s[256], cur[256];
    __shared__ int stage[STG];
    int t = threadIdx.x, bin = blockIdx.x;
    int ebase = binB[bin], eend = binB[bin + 1];
    int n = eend - ebase;
    cnt[t] = 0;
    __syncthreads();
    for (int p = ebase + t; p < eend; p += 256)
        atomicAdd(&cnt[edgepk[p] & 255], 1);
    __syncthreads();
    s[t] = cnt[t];
    __syncthreads();
    for (int off = 1; off < 256; off <<= 1) {
        int v = (t >= off) ? s[t - off] : 0;
        __syncthreads();
        if (t >= off) s[t] += v;
        __syncthreads();
    }
    int excl = t ? s[t - 1] : 0;
    int node = (bin << 8) + t;
    if (node < N_NODES) {
        dinv[node] = rsqrtf((float)(cnt[t] + 1));
        row_ptr[node] = ebase + excl;
    }
    cur[t] = excl;
    __syncthreads();
    for (int p = ebase + t; p < eend; p += 256) {
        int w = edgepk[p];
        int l = atomicAdd(&cur[w & 255], 1);
        int sv = w >> 8;
        if (l < STG) stage[l] = sv;
        else csr[ebase + l] = sv;
    }
    __syncthreads();
    int lim = min(n, STG);
    for (int l = t; l < lim; l += 256)
        csr[ebase + l] = stage[l];
}

// ---------- B(bf16) = (x @ W1) * dinv[row], register-tiled (4 ch/thread) ----------
#define XS1 132               // 128 + 4 pad
__global__ __launch_bounds__(256) void gemm1_kernel(const float* __restrict__ x,
                                                    const float* __restrict__ W1,
                                                    const float* __restrict__ dinv,
                                                    unsigned* __restrict__ Bu) {
    __shared__ float Wl[IN_CH * HID];   // 16 KB
    __shared__ float xs[32 * XS1];      // 16.9 KB
    int tid = threadIdx.x;
    for (int j = tid; j < IN_CH * HID / 4; j += 256)
        ((float4*)Wl)[j] = ((const float4*)W1)[j];
    int row0 = blockIdx.x * 32;         // 100000 % 32 == 0
    const float4* x4 = (const float4*)(x + (size_t)row0 * IN_CH);
    for (int j = tid; j < 32 * IN_CH / 4; j += 256) {
        int r = j >> 5, k4 = j & 31;
        ((float4*)&xs[r * XS1])[k4] = x4[j];
    }
    __syncthreads();
    int r = tid >> 3, cg = (tid & 7) * 4;
    const float* xr = &xs[r * XS1];
    float4 acc = {0.f, 0.f, 0.f, 0.f};
    #pragma unroll 8
    for (int k = 0; k < IN_CH; ++k) {
        float xv = xr[k];
        float4 w = *(const float4*)&Wl[k * HID + cg];
        acc.x += xv * w.x; acc.y += xv * w.y; acc.z += xv * w.z; acc.w += xv * w.w;
    }
    int row = row0 + r;
    float dv = dinv[row];
    uint2 p;
    p.x = bfr(acc.x * dv) | (bfr(acc.y * dv) << 16);
    p.y = bfr(acc.z * dv) | (bfr(acc.w * dv) << 16);
    *(uint2*)&Bu[(size_t)row * 16 + (tid & 7) * 2] = p;
}

// ---------- B(bf16) = (in @ W2) * dinv[row], register-tiled ----------
#define XS2 36                // 32 + 4 pad
__global__ __launch_bounds__(256) void gemm2_kernel(const float* __restrict__ in,
                                                    const float* __restrict__ W2,
                                                    const float* __restrict__ dinv,
                                                    unsigned* __restrict__ Bu) {
    __shared__ float Wl[HID * HID];     // 4 KB
    __shared__ float xs[32 * XS2];      // 4.6 KB
    int tid = threadIdx.x;
    ((float4*)Wl)[tid] = ((const float4*)W2)[tid];
    int row0 = blockIdx.x * 32;
    const float4* in4 = (const float4*)(in + (size_t)row0 * HID);
    {
        int r = tid >> 3, k4 = tid & 7;
        ((float4*)&xs[r * XS2])[k4] = in4[tid];
    }
    __syncthreads();
    int r = tid >> 3, cg = (tid & 7) * 4;
    const float* xr = &xs[r * XS2];
    float4 acc = {0.f, 0.f, 0.f, 0.f};
    #pragma unroll
    for (int k = 0; k < HID; ++k) {
        float xv = xr[k];
        float4 w = *(const float4*)&Wl[k * HID + cg];
        acc.x += xv * w.x; acc.y += xv * w.y; acc.z += xv * w.z; acc.w += xv * w.w;
    }
    int row = row0 + r;
    float dv = dinv[row];
    uint2 p;
    p.x = bfr(acc.x * dv) | (bfr(acc.y * dv) << 16);
    p.y = bfr(acc.z * dv) | (bfr(acc.w * dv) << 16);
    *(uint2*)&Bu[(size_t)row * 16 + (tid & 7) * 2] = p;
}

// ---------- gather layer: bf16 B, 16 lanes/node (2 ch each), 8-wide MLP unroll ----------
__global__ __launch_bounds__(256) void layer_kernel(const unsigned* __restrict__ Bu,
                                                    const int* __restrict__ csr,
                                                    const int* __restrict__ row_ptr,
                                                    const float* __restrict__ dinv,
                                                    const float* __restrict__ bias,
                                                    float* __restrict__ out,
                                                    int relu) {
    int tid = threadIdx.x;
    int node = blockIdx.x * 16 + (tid >> 4);   // grid 6250 -> exactly 100000 nodes
    int c2 = tid & 15;
    unsigned ws = Bu[(size_t)node * 16 + c2];
    float a0 = bflo(ws), a1 = bfhi(ws);
    int j = row_ptr[node], re = row_ptr[node + 1];
    for (; j + 8 <= re; j += 8) {
        int s0 = csr[j + 0], s1 = csr[j + 1], s2 = csr[j + 2], s3 = csr[j + 3];
        int s4 = csr[j + 4], s5 = csr[j + 5], s6 = csr[j + 6], s7 = csr[j + 7];
        unsigned w0 = Bu[(size_t)s0 * 16 + c2], w1 = Bu[(size_t)s1 * 16 + c2];
        unsigned w2 = Bu[(size_t)s2 * 16 + c2], w3 = Bu[(size_t)s3 * 16 + c2];
        unsigned w4 = Bu[(size_t)s4 * 16 + c2], w5 = Bu[(size_t)s5 * 16 + c2];
        unsigned w6 = Bu[(size_t)s6 * 16 + c2], w7 = Bu[(size_t)s7 * 16 + c2];
        a0 += ((bflo(w0) + bflo(w1)) + (bflo(w2) + bflo(w3)))
            + ((bflo(w4) + bflo(w5)) + (bflo(w6) + bflo(w7)));
        a1 += ((bfhi(w0) + bfhi(w1)) + (bfhi(w2) + bfhi(w3)))
            + ((bfhi(w4) + bfhi(w5)) + (bfhi(w6) + bfhi(w7)));
    }
    if (j + 4 <= re) {
        int s0 = csr[j], s1 = csr[j + 1], s2 = csr[j + 2], s3 = csr[j + 3];
        unsigned w0 = Bu[(size_t)s0 * 16 + c2], w1 = Bu[(size_t)s1 * 16 + c2];
        unsigned w2 = Bu[(size_t)s2 * 16 + c2], w3 = Bu[(size_t)s3 * 16 + c2];
        a0 += (bflo(w0) + bflo(w1)) + (bflo(w2) + bflo(w3));
        a1 += (bfhi(w0) + bfhi(w1)) + (bfhi(w2) + bfhi(w3));
        j += 4;
    }
    for (; j < re; ++j) {
        unsigned w = Bu[(size_t)csr[j] * 16 + c2];
        a0 += bflo(w); a1 += bfhi(w);
    }
    float dv = dinv[node];
    float2 o;
    o.x = a0 * dv + bias[2 * c2];
    o.y = a1 * dv + bias[2 * c2 + 1];
    if (relu) { o.x = fmaxf(o.x, 0.f); o.y = fmaxf(o.y, 0.f); }
    *(float2*)&out[(size_t)node * HID + 2 * c2] = o;
}

// ---------- per-graph mean-pool: register run-accumulation + span flush ----------
__global__ __launch_bounds__(256) void pool_kernel(const float* __restrict__ h,
                                                   const int* __restrict__ batch,
                                                   float* __restrict__ gsum,
                                                   float* __restrict__ cnt) {
    __shared__ float pool[N_GRAPHS * HID];  // 8 KB
    __shared__ float cntl[N_GRAPHS];
    __shared__ int gmin, gmax;
    int t = threadIdx.x;
    for (int j = t; j < N_GRAPHS * HID; j += 256) pool[j] = 0.f;
    if (t < N_GRAPHS) cntl[t] = 0.f;
    if (t == 0) { gmin = N_GRAPHS; gmax = -1; }
    __syncthreads();
    int start = blockIdx.x * 256;
    int end = min(start + 256, N_NODES);
    int c = t & 31;
    float racc = 0.f;
    int rg = -1, rcnt = 0;
    for (int nb = start + (t >> 5); nb < end; nb += 8) {
        float v = h[(size_t)nb * HID + c];
        int g = batch[nb];
        if (g != rg) {
            if ((unsigned)rg < N_GRAPHS) {
                atomicAdd(&pool[rg * HID + c], racc);
                if (c == 0) {
                    atomicAdd(&cntl[rg], (float)rcnt);
                    atomicMin(&gmin, rg); atomicMax(&gmax, rg);
                }
            }
            rg = g; racc = v; rcnt = 1;
        } else { racc += v; ++rcnt; }
    }
    if ((unsigned)rg < N_GRAPHS) {
        atomicAdd(&pool[rg * HID + c], racc);
        if (c == 0) {
            atomicAdd(&cntl[rg], (float)rcnt);
            atomicMin(&gmin, rg); atomicMax(&gmax, rg);
        }
    }
    __syncthreads();
    int lo = gmin, hi = gmax;
    if (hi >= lo) {
        int span = (hi - lo + 1) * HID;
        for (int j = t; j < span; j += 256)
            atomicAdd(&gsum[lo * HID + j], pool[lo * HID + j]);
        for (int j = t; j <= hi - lo; j += 256)
            atomicAdd(&cnt[lo + j], cntl[lo + j]);
    }
}

__global__ void summary_kernel(const float* __restrict__ gsum, const float* __restrict__ cnt,
                               const float* __restrict__ Ws, const float* __restrict__ bs,
                               float* __restrict__ out) {
    int g = blockIdx.x, c = threadIdx.x;
    float inv = 1.f / fmaxf(cnt[g], 1.f);
    float acc = bs[c];
    #pragma unroll
    for (int k = 0; k < HID; ++k)
        acc += gsum[g * HID + k] * inv * Ws[k * HID + c];
    out[g * HID + c] = acc;
}

extern "C" void kernel_launch(void* const* d_in, const int* in_sizes, int n_in,
                              void* d_out, int out_size, void* d_ws, size_t ws_size,
                              hipStream_t stream) {
    const float* x    = (const float*)d_in[0];
    const int* edge   = (const int*)d_in[1];
    const int* src    = edge;
    const int* dst    = edge + N_EDGES;
    const int* batch  = (const int*)d_in[2];
    const float* W1   = (const float*)d_in[3];
    const float* b1   = (const float*)d_in[4];
    const float* W2   = (const float*)d_in[5];
    const float* b2   = (const float*)d_in[6];
    const float* Ws   = (const float*)d_in[7];
    const float* bs   = (const float*)d_in[8];

    float* ws      = (float*)d_ws;
    unsigned* Bu   = (unsigned*)(ws + OFF_B);   // bf16-packed B
    int*   H       = (int*)(ws + OFF_B);        // aliases B head; dead before gemm1
    int*   edgepk  = (int*)(ws + OFF_EDGEPK);
    int*   csr     = (int*)(ws + OFF_CSR);
    int*   colT    = (int*)(ws + OFF_COLT);
    int*   binB    = (int*)(ws + OFF_BINB);
    int*   row_ptr = (int*)(ws + OFF_ROWPTR);
    float* dinv    = ws + OFF_DINV;
    float* gsum    = ws + OFF_EDGEPK;           // aliases edgepk (dead after csr2)
    float* cnt     = gsum + N_GRAPHS * HID;

    float* out     = (float*)d_out;
    float* out_sum = out;
    float* out_h   = out + N_GRAPHS * HID;

    // CSR build
    hist_kernel    <<<MGRID, 512, 0, stream>>>(dst, H);
    scanrow_kernel <<<NBIN,  512, 0, stream>>>(H, colT);
    scanbase_kernel<<<1,     512, 0, stream>>>(colT, binB, row_ptr);
    msplit_kernel  <<<MGRID, 512, 0, stream>>>(src, dst, H, binB, edgepk);
    csr2_kernel    <<<NBIN,  256, 0, stream>>>(edgepk, binB, row_ptr, dinv, csr);

    // layer 1
    gemm1_kernel<<<N_NODES / 32, 256, 0, stream>>>(x, W1, dinv, Bu);
    layer_kernel<<<N_NODES / 16, 256, 0, stream>>>(Bu, csr, row_ptr, dinv, b1, out_h, 1);

    // layer 2
    gemm2_kernel<<<N_NODES / 32, 256, 0, stream>>>(out_h, W2, dinv, Bu);
    layer_kernel<<<N_NODES / 16, 256, 0, stream>>>(Bu, csr, row_ptr, dinv, b2, out_h, 0);

    // pooling + summary
    hipMemsetAsync(gsum, 0, (N_GRAPHS * HID + N_GRAPHS) * sizeof(float), stream);
    pool_kernel<<<NBIN, 256, 0, stream>>>(out_h, batch, gsum, cnt);
    summary_kernel<<<N_GRAPHS, HID, 0, stream>>>(gsum, cnt, Ws, bs, out_sum);
}